// Round 6
// baseline (251.918 us; speedup 1.0000x reference)
//
#include <hip/hip_runtime.h>
#include <math.h>

#define D 100
#define NEG_SLOPE 0.2f
#define CHUNK 16
#define ROWU 52          // uints per packed-f16 row, padded 50->52 for 16B align
#define NPB 2            // nodes (waves) per block
#define EPR 8            // epilogue transpose rows (two rounds of 8 pairs)
#define TRW 108          // transpose row width in floats (104 + pad); stride
                         // 108 floats -> 2-way bank aliasing on reads (free)

// compiler-only memory barrier (validated R17: same-wave LDS is pipe-ordered)
#define COMPILER_FENCE() asm volatile("" ::: "memory")

typedef _Float16 f16x2 __attribute__((ext_vector_type(2)));
union U32H2 { unsigned int u; f16x2 h; };

__device__ __forceinline__ unsigned int pkh2(float x, float y) {
    U32H2 c; c.h.x = (_Float16)x; c.h.y = (_Float16)y; return c.u;
}

// 2-wide f16 dot + fp32 accumulate: v_dot2_f32_f16
__device__ __forceinline__ float dot2u(unsigned int au, unsigned int xu, float acc) {
#if __has_builtin(__builtin_amdgcn_fdot2)
    U32H2 a, x; a.u = au; x.u = xu;
    return __builtin_amdgcn_fdot2(a.h, x.h, acc, false);
#else
    U32H2 a, x; a.u = au; x.u = xu;
    return acc + (float)a.h.x * (float)x.h.x + (float)a.h.y * (float)x.h.y;
#endif
}

// DPP cross-lane (VALU pipe).
template<int CTRL>
__device__ __forceinline__ float dppf(float x) {
    return __uint_as_float((unsigned)__builtin_amdgcn_update_dpp(
        0, (int)__float_as_uint(x), CTRL, 0xF, 0xF, true));
}
__device__ __forceinline__ float red16_max(float x) {
    x = fmaxf(x, dppf<0xB1>(x));    // quad_perm xor1
    x = fmaxf(x, dppf<0x4E>(x));    // quad_perm xor2
    x = fmaxf(x, dppf<0x124>(x));   // row_ror:4
    x = fmaxf(x, dppf<0x128>(x));   // row_ror:8
    return x;
}
__device__ __forceinline__ float red16_sum(float x) {
    x += dppf<0xB1>(x);
    x += dppf<0x4E>(x);
    x += dppf<0x124>(x);
    x += dppf<0x128>(x);
    return x;
}

// Fused prep: t < P: row_ptr boundary scatter; t < total25: fp32 -> f16 pack.
__global__ void prep_kernel(const int* __restrict__ seg,
                            int* __restrict__ row_ptr,
                            const float* __restrict__ hidden,
                            unsigned int* __restrict__ hb,
                            int n, int P, int total25)
{
    int t = blockIdx.x * blockDim.x + threadIdx.x;
    if (t < P) {
        int s0 = seg[t];
        if (t == 0)
            for (int v = 0; v <= s0; v++) row_ptr[v] = 0;
        int s1 = (t + 1 < P) ? seg[t + 1] : n;
        for (int v = s0 + 1; v <= s1; v++) row_ptr[v] = t + 1;
    }
    if (t < total25) {
        int node = t / 25, k = t - node * 25;   // 25 float4-groups per row
        float4 f = ((const float4*)hidden)[t];
        *(uint2*)&hb[node * ROWU + 2 * k] =
            make_uint2(pkh2(f.x, f.y), pkh2(f.z, f.w));
    }
}

// accumulate one uint4 (8 f16 dims) into accA[b..b+7] via v_fma_mix
#define ACCU4(b, X) do {                                                      \
    U32H2 t_;                                                                 \
    t_.u = (X).x; accA[(b)+0] = fmaf((float)t_.h.x, e, accA[(b)+0]);          \
                  accA[(b)+1] = fmaf((float)t_.h.y, e, accA[(b)+1]);          \
    t_.u = (X).y; accA[(b)+2] = fmaf((float)t_.h.x, e, accA[(b)+2]);          \
                  accA[(b)+3] = fmaf((float)t_.h.y, e, accA[(b)+3]);          \
    t_.u = (X).z; accA[(b)+4] = fmaf((float)t_.h.x, e, accA[(b)+4]);          \
                  accA[(b)+5] = fmaf((float)t_.h.y, e, accA[(b)+5]);          \
    t_.u = (X).w; accA[(b)+6] = fmaf((float)t_.h.x, e, accA[(b)+6]);          \
                  accA[(b)+7] = fmaf((float)t_.h.y, e, accA[(b)+7]);          \
} while (0)

// write this lane's quarter accumulators into transpose row r (0..7)
#define TR_WRITE(r) do {                                                      \
    float* trow_ = &s_tr[wid][(r)][24 * q];                                   \
    *(float4*)&trow_[0]  = make_float4(accA[0],  accA[1],  accA[2],  accA[3]);\
    *(float4*)&trow_[4]  = make_float4(accA[4],  accA[5],  accA[6],  accA[7]);\
    *(float4*)&trow_[8]  = make_float4(accA[8],  accA[9],  accA[10], accA[11]);\
    *(float4*)&trow_[12] = make_float4(accA[12], accA[13], accA[14], accA[15]);\
    *(float4*)&trow_[16] = make_float4(accA[16], accA[17], accA[18], accA[19]);\
    *(float4*)&trow_[20] = make_float4(accA[20], accA[21], accA[22], accA[23]);\
    if (q == 0)                                                               \
        *(float4*)&s_tr[wid][(r)][96] =                                       \
            make_float4(accT[0], accT[1], accT[2], accT[3]);                  \
} while (0)

// One wave per node, CHUNK=16, 4 lanes/pair. R6 = R5's register-accumulator
// main loop (no per-chunk LDS staging / phase-B reads) + a HALVED epilogue
// transpose buffer: the cross-pair reduction runs in two rounds of 8 pair-
// rows reusing one 8-row buffer (same-wave LDS is pipe-ordered; fences only).
// Rationale: R0/R3/R5 all show VALU-busy time invariant ~27us and wall ~
// VALU-time/occupancy; R5's 14.3KB LDS capped residency at 22 waves (occ 46%,
// 59us). This restores R3's ~7.4KB footprint (32-wave cap) while keeping
// LDS-pipe cost ~180cy/node vs R0's ~437.
__launch_bounds__(64 * NPB, 8)
__global__ void gat_agg_kernel(const float* __restrict__ hidden,
                               const float* __restrict__ W,
                               const int* __restrict__ nbr,
                               const int* __restrict__ row_ptr,
                               const unsigned int* __restrict__ hb,
                               float* __restrict__ out,
                               int n, int P)
{
    __shared__ __align__(16) unsigned int s_hwp[NPB][ROWU];       // 0.42 KB
    __shared__ __align__(16) float        s_tr[NPB][EPR][TRW];    // 6.9 KB

    const int lane = threadIdx.x & 63;
    const int wid  = threadIdx.x >> 6;
    const int v    = blockIdx.x * NPB + wid;
    if (v >= n) return;          // wave-uniform exit; no block barriers used

    // hw[d] = hidden[v][d] * W[d] (fp32 product, f16-packed into LDS)
    if (lane < 50) {
        float2 h2 = ((const float2*)(hidden + (long)v * D))[lane];
        float2 w2 = ((const float2*)W)[lane];
        s_hwp[wid][lane] = pkh2(h2.x * w2.x, h2.y * w2.y);
    }
    COMPILER_FENCE();

    const int start = row_ptr[v];
    const int end   = row_ptr[v + 1];

    if (end <= start) {          // empty segment: zeros (matches reference)
        if (lane < D / 2)
            ((float2*)(out + (long)v * D))[lane] = make_float2(0.f, 0.f);
        return;
    }

    const int q  = lane >> 4;    // quarter 0..3: uint4s q*3..q*3+2 (+tail on q0)
    const int jl = lane & 15;    // pair slot within the 16-chunk
    const int t0 = q * 3;

    // hoist hw fragment into registers (loop-invariant; 14 regs)
    const uint4* hwq = ((const uint4*)&s_hwp[wid][0]) + t0;
    const uint4 a0 = hwq[0], a1 = hwq[1], a2 = hwq[2];
    uint2 at = make_uint2(0u, 0u);
    if (q == 0) at = *(const uint2*)&s_hwp[wid][48];

    // register accumulators: quarter dims 24q..24q+23, plus tail 96..99 on q0
    float accA[24];
    float accT[4];
    #pragma unroll
    for (int i = 0; i < 24; ++i) accA[i] = 0.f;
    #pragma unroll
    for (int i = 0; i < 4; ++i) accT[i] = 0.f;

    float m = -INFINITY, z = 0.f;

    for (int c = start; c < end; c += CHUNK) {
        const int  cnt = min(CHUNK, end - c);
        const bool pv  = jl < cnt;

        // neighbor index: coalesced masked load. invalid lanes use row 0
        // (finite, in-bounds, L1-hot); e=0 masks them later.
        const int nbv = pv ? nbr[c + jl] : 0;
        const uint4* row16 = ((const uint4*)hb) + nbv * (ROWU / 4) + t0;

        // ---- f16 quarter-row gather (3x16B + 8B tail on q0), fdot2 ----
        uint4 x0 = row16[0], x1 = row16[1], x2 = row16[2];
        uint2 xt = make_uint2(0u, 0u);
        if (q == 0) xt = *(const uint2*)&hb[nbv * ROWU + 48];   // dims 96..99

        float p0 = 0.f, p1 = 0.f, p2 = 0.f, p3 = 0.f;
        p0 = dot2u(a0.x, x0.x, p0);  p1 = dot2u(a0.y, x0.y, p1);
        p2 = dot2u(a0.z, x0.z, p2);  p3 = dot2u(a0.w, x0.w, p3);
        p0 = dot2u(a1.x, x1.x, p0);  p1 = dot2u(a1.y, x1.y, p1);
        p2 = dot2u(a1.z, x1.z, p2);  p3 = dot2u(a1.w, x1.w, p3);
        p0 = dot2u(a2.x, x2.x, p0);  p1 = dot2u(a2.y, x2.y, p1);
        p2 = dot2u(a2.z, x2.z, p2);  p3 = dot2u(a2.w, x2.w, p3);
        if (q == 0) {
            p0 = dot2u(at.x, xt.x, p0);
            p1 = dot2u(at.y, xt.y, p1);
        }

        float part = (p0 + p1) + (p2 + p3);
        part += __shfl_xor(part, 16, 64);    // combine quarters; after these
        part += __shfl_xor(part, 32, 64);    // ALL 4 lanes hold the pair score
        const float s = pv ? (part >= 0.f ? part : NEG_SLOPE * part)
                           : -INFINITY;

        // ---- online softmax over the 16 pairs (DPP trees, wave-uniform m) --
        const float m_new = fmaxf(m, red16_max(s));
        const float e     = pv ? __expf(s - m_new) : 0.f;
        const float gsum  = red16_sum(e);

        if (m_new != m) {                    // wave-uniform; scale==1 if equal
            const float scale = __expf(m - m_new);   // first chunk: 0
            z *= scale;
            #pragma unroll
            for (int i = 0; i < 24; ++i) accA[i] *= scale;
            #pragma unroll
            for (int i = 0; i < 4; ++i) accT[i] *= scale;
            m = m_new;
        }
        z += gsum;

        // ---- accumulate e * row into register accumulators (v_fma_mix) ----
        ACCU4(0,  x0);
        ACCU4(8,  x1);
        ACCU4(16, x2);
        if (q == 0) {
            U32H2 t_;
            t_.u = xt.x; accT[0] = fmaf((float)t_.h.x, e, accT[0]);
                         accT[1] = fmaf((float)t_.h.y, e, accT[1]);
            t_.u = xt.y; accT[2] = fmaf((float)t_.h.x, e, accT[2]);
                         accT[3] = fmaf((float)t_.h.y, e, accT[3]);
        }
    }

    // ---- epilogue: cross-pair reduction via 8-row LDS transpose, 2 rounds --
    // round A: pairs 0..7 write rows 0..7
    if (jl < EPR) TR_WRITE(jl);
    COMPILER_FENCE();

    float sx = 0.f, sy = 0.f;
    if (lane < D / 2) {
        #pragma unroll
        for (int p = 0; p < EPR; ++p) {
            const float2 t = *(const float2*)&s_tr[wid][p][2 * lane];
            sx += t.x; sy += t.y;
        }
    }
    COMPILER_FENCE();            // round-A reads before round-B overwrites

    // round B: pairs 8..15 reuse rows 0..7
    if (jl >= EPR) TR_WRITE(jl - EPR);
    COMPILER_FENCE();

    if (lane < D / 2) {
        #pragma unroll
        for (int p = 0; p < EPR; ++p) {
            const float2 t = *(const float2*)&s_tr[wid][p][2 * lane];
            sx += t.x; sy += t.y;
        }
        const float inv = 1.f / z;           // z wave-uniform
        ((float2*)(out + (long)v * D))[lane] = make_float2(sx * inv, sy * inv);
    }
}

extern "C" void kernel_launch(void* const* d_in, const int* in_sizes, int n_in,
                              void* d_out, int out_size, void* d_ws, size_t ws_size,
                              hipStream_t stream) {
    const float* hidden = (const float*)d_in[0];
    const float* W      = (const float*)d_in[1];
    const int*   seg    = (const int*)d_in[2];
    const int*   nbr    = (const int*)d_in[3];
    float*       out    = (float*)d_out;

    const int Ddim = in_sizes[1];           // 100
    const int n    = in_sizes[0] / Ddim;    // 50000
    const int P    = in_sizes[2];           // ~1.3M pairs

    // ws layout: row_ptr (n+1 ints) | hb (n*ROWU uints, 256B-aligned)
    int* row_ptr = (int*)d_ws;
    size_t hb_off = (((size_t)(n + 1) * 4) + 255) & ~(size_t)255;
    unsigned int* hb = (unsigned int*)((char*)d_ws + hb_off);

    const int total25 = n * 25;             // float4-groups in hidden
    const int tmax    = (P > total25) ? P : total25;
    hipLaunchKernelGGL(prep_kernel, dim3((tmax + 255) / 256), dim3(256), 0, stream,
                       seg, row_ptr, hidden, hb, n, P, total25);
    hipLaunchKernelGGL(gat_agg_kernel, dim3((n + NPB - 1) / NPB), dim3(64 * NPB),
                       0, stream, hidden, W, nbr, row_ptr, hb, out, n, P);
}

// Round 8
// 220.463 us; speedup vs baseline: 1.1427x; 1.1427x over previous
//
#include <hip/hip_runtime.h>
#include <math.h>

#define D 100
#define NEG_SLOPE 0.2f
#define CHUNK 16
#define ROWU 52          // uints per packed-f16 row, padded 50->52 for 16B align
#define NPB 2            // nodes (waves) per block

// compiler-only memory barrier (validated R17: same-wave LDS is pipe-ordered)
#define COMPILER_FENCE() asm volatile("" ::: "memory")

typedef _Float16 f16x2 __attribute__((ext_vector_type(2)));
union U32H2 { unsigned int u; f16x2 h; };

__device__ __forceinline__ unsigned int pkh2(float x, float y) {
    U32H2 c; c.h.x = (_Float16)x; c.h.y = (_Float16)y; return c.u;
}

// 2-wide f16 dot + fp32 accumulate: v_dot2_f32_f16
__device__ __forceinline__ float dot2u(unsigned int au, unsigned int xu, float acc) {
#if __has_builtin(__builtin_amdgcn_fdot2)
    U32H2 a, x; a.u = au; x.u = xu;
    return __builtin_amdgcn_fdot2(a.h, x.h, acc, false);
#else
    U32H2 a, x; a.u = au; x.u = xu;
    return acc + (float)a.h.x * (float)x.h.x + (float)a.h.y * (float)x.h.y;
#endif
}

// DPP cross-lane (VALU pipe).
template<int CTRL>
__device__ __forceinline__ float dppf(float x) {
    return __uint_as_float((unsigned)__builtin_amdgcn_update_dpp(
        0, (int)__float_as_uint(x), CTRL, 0xF, 0xF, true));
}
__device__ __forceinline__ float red16_max(float x) {
    x = fmaxf(x, dppf<0xB1>(x));    // quad_perm xor1
    x = fmaxf(x, dppf<0x4E>(x));    // quad_perm xor2
    x = fmaxf(x, dppf<0x124>(x));   // row_ror:4
    x = fmaxf(x, dppf<0x128>(x));   // row_ror:8
    return x;
}
__device__ __forceinline__ float red16_sum(float x) {
    x += dppf<0xB1>(x);
    x += dppf<0x4E>(x);
    x += dppf<0x124>(x);
    x += dppf<0x128>(x);
    return x;
}

// Fused prep: t < P: row_ptr boundary scatter; t < total25: fp32 -> f16 pack.
__global__ void prep_kernel(const int* __restrict__ seg,
                            int* __restrict__ row_ptr,
                            const float* __restrict__ hidden,
                            unsigned int* __restrict__ hb,
                            int n, int P, int total25)
{
    int t = blockIdx.x * blockDim.x + threadIdx.x;
    if (t < P) {
        int s0 = seg[t];
        if (t == 0)
            for (int v = 0; v <= s0; v++) row_ptr[v] = 0;
        int s1 = (t + 1 < P) ? seg[t + 1] : n;
        for (int v = s0 + 1; v <= s1; v++) row_ptr[v] = t + 1;
    }
    if (t < total25) {
        int node = t / 25, k = t - node * 25;   // 25 float4-groups per row
        float4 f = ((const float4*)hidden)[t];
        *(uint2*)&hb[node * ROWU + 2 * k] =
            make_uint2(pkh2(f.x, f.y), pkh2(f.z, f.w));
    }
}

// accumulate one uint4 (8 f16 dims) into accA[b..b+7] via v_fma_mix
#define ACCU4(b, X) do {                                                      \
    U32H2 t_;                                                                 \
    t_.u = (X).x; accA[(b)+0] = fmaf((float)t_.h.x, e, accA[(b)+0]);          \
                  accA[(b)+1] = fmaf((float)t_.h.y, e, accA[(b)+1]);          \
    t_.u = (X).y; accA[(b)+2] = fmaf((float)t_.h.x, e, accA[(b)+2]);          \
                  accA[(b)+3] = fmaf((float)t_.h.y, e, accA[(b)+3]);          \
    t_.u = (X).z; accA[(b)+4] = fmaf((float)t_.h.x, e, accA[(b)+4]);          \
                  accA[(b)+5] = fmaf((float)t_.h.y, e, accA[(b)+5]);          \
    t_.u = (X).w; accA[(b)+6] = fmaf((float)t_.h.x, e, accA[(b)+6]);          \
                  accA[(b)+7] = fmaf((float)t_.h.y, e, accA[(b)+7]);          \
} while (0)

// One wave per node, CHUNK=16, 4 lanes/pair. R7 = R5's register-accumulator
// main loop + a ZERO-LDS split-butterfly epilogue: cross-pair reduction in
// registers, payload halving each exchange (xor8/xor2/xor1 splits via DPP,
// final 3-float xor4 full-butterfly via shfl). No conditional LDS writes, no
// epilogue fences, static register indexing only — R6's conditional LDS
// epilogue triggered a catastrophic accA scratch spill (VGPR 32, WRITE_SIZE
// 362MB, 173us). LDS shrinks to s_hwp only (0.42KB) -> 16wg x 2 = 32-wave
// cap. Measured law from R3/R5: occupancy = 0.66 x cap/32, wall ~ 1/occ.
// (R8 resubmit: R7 bench died to container infra, not the kernel — code
// audited for OOB/spill risk and re-derived the butterfly; unchanged.)
__launch_bounds__(64 * NPB, 8)
__global__ void gat_agg_kernel(const float* __restrict__ hidden,
                               const float* __restrict__ W,
                               const int* __restrict__ nbr,
                               const int* __restrict__ row_ptr,
                               const unsigned int* __restrict__ hb,
                               float* __restrict__ out,
                               int n, int P)
{
    __shared__ __align__(16) unsigned int s_hwp[NPB][ROWU];       // 0.42 KB

    const int lane = threadIdx.x & 63;
    const int wid  = threadIdx.x >> 6;
    const int v    = blockIdx.x * NPB + wid;
    if (v >= n) return;          // wave-uniform exit; no block barriers used

    // hw[d] = hidden[v][d] * W[d] (fp32 product, f16-packed into LDS)
    if (lane < 50) {
        float2 h2 = ((const float2*)(hidden + (long)v * D))[lane];
        float2 w2 = ((const float2*)W)[lane];
        s_hwp[wid][lane] = pkh2(h2.x * w2.x, h2.y * w2.y);
    }
    COMPILER_FENCE();

    const int start = row_ptr[v];
    const int end   = row_ptr[v + 1];

    if (end <= start) {          // empty segment: zeros (matches reference)
        if (lane < D / 2)
            ((float2*)(out + (long)v * D))[lane] = make_float2(0.f, 0.f);
        return;
    }

    const int q  = lane >> 4;    // quarter 0..3: uint4s q*3..q*3+2 (+tail on q0)
    const int jl = lane & 15;    // pair slot within the 16-chunk
    const int t0 = q * 3;

    // hoist hw fragment into registers (loop-invariant; 14 regs)
    const uint4* hwq = ((const uint4*)&s_hwp[wid][0]) + t0;
    const uint4 a0 = hwq[0], a1 = hwq[1], a2 = hwq[2];
    uint2 at = make_uint2(0u, 0u);
    if (q == 0) at = *(const uint2*)&s_hwp[wid][48];

    // register accumulators: quarter dims 24q..24q+23, plus tail 96..99 on q0
    float accA[24];
    float accT[4];
    #pragma unroll
    for (int i = 0; i < 24; ++i) accA[i] = 0.f;
    #pragma unroll
    for (int i = 0; i < 4; ++i) accT[i] = 0.f;

    float m = -INFINITY, z = 0.f;

    for (int c = start; c < end; c += CHUNK) {
        const int  cnt = min(CHUNK, end - c);
        const bool pv  = jl < cnt;

        // neighbor index: coalesced masked load. invalid lanes use row 0
        // (finite, in-bounds, L1-hot); e=0 masks them later.
        const int nbv = pv ? nbr[c + jl] : 0;
        const uint4* row16 = ((const uint4*)hb) + nbv * (ROWU / 4) + t0;

        // ---- f16 quarter-row gather (3x16B + 8B tail on q0), fdot2 ----
        uint4 x0 = row16[0], x1 = row16[1], x2 = row16[2];
        uint2 xt = make_uint2(0u, 0u);
        if (q == 0) xt = *(const uint2*)&hb[nbv * ROWU + 48];   // dims 96..99

        float p0 = 0.f, p1 = 0.f, p2 = 0.f, p3 = 0.f;
        p0 = dot2u(a0.x, x0.x, p0);  p1 = dot2u(a0.y, x0.y, p1);
        p2 = dot2u(a0.z, x0.z, p2);  p3 = dot2u(a0.w, x0.w, p3);
        p0 = dot2u(a1.x, x1.x, p0);  p1 = dot2u(a1.y, x1.y, p1);
        p2 = dot2u(a1.z, x1.z, p2);  p3 = dot2u(a1.w, x1.w, p3);
        p0 = dot2u(a2.x, x2.x, p0);  p1 = dot2u(a2.y, x2.y, p1);
        p2 = dot2u(a2.z, x2.z, p2);  p3 = dot2u(a2.w, x2.w, p3);
        if (q == 0) {
            p0 = dot2u(at.x, xt.x, p0);
            p1 = dot2u(at.y, xt.y, p1);
        }

        float part = (p0 + p1) + (p2 + p3);
        part += __shfl_xor(part, 16, 64);    // combine quarters; after these
        part += __shfl_xor(part, 32, 64);    // ALL 4 lanes hold the pair score
        const float s = pv ? (part >= 0.f ? part : NEG_SLOPE * part)
                           : -INFINITY;

        // ---- online softmax over the 16 pairs (DPP trees, wave-uniform m) --
        const float m_new = fmaxf(m, red16_max(s));
        const float e     = pv ? __expf(s - m_new) : 0.f;
        const float gsum  = red16_sum(e);

        if (m_new != m) {                    // wave-uniform; scale==1 if equal
            const float scale = __expf(m - m_new);   // first chunk: 0
            z *= scale;
            #pragma unroll
            for (int i = 0; i < 24; ++i) accA[i] *= scale;
            #pragma unroll
            for (int i = 0; i < 4; ++i) accT[i] *= scale;
            m = m_new;
        }
        z += gsum;

        // ---- accumulate e * row into register accumulators (v_fma_mix) ----
        ACCU4(0,  x0);
        ACCU4(8,  x1);
        ACCU4(16, x2);
        if (q == 0) {
            U32H2 t_;
            t_.u = xt.x; accT[0] = fmaf((float)t_.h.x, e, accT[0]);
                         accT[1] = fmaf((float)t_.h.y, e, accT[1]);
            t_.u = xt.y; accT[2] = fmaf((float)t_.h.x, e, accT[2]);
                         accT[3] = fmaf((float)t_.h.y, e, accT[3]);
        }
    }

    const float inv = 1.f / z;               // z wave-uniform
    float* orow = out + (long)v * D;

    // ---- tail first (frees accT early): full DPP-16 reduce of dims 96..99 --
    const float T0 = red16_sum(accT[0]) * inv;
    const float T1 = red16_sum(accT[1]) * inv;
    const float T2 = red16_sum(accT[2]) * inv;
    const float T3 = red16_sum(accT[3]) * inv;
    if (lane == 0) ((float2*)orow)[48] = make_float2(T0, T1);
    if (lane == 1) ((float2*)orow)[49] = make_float2(T2, T3);

    // ---- split-butterfly cross-pair reduction (registers only) ----
    // each exchange halves the payload; kept half selected by a jl bit.
    const bool b8 = (jl & 8) != 0;
    const bool b4 = (jl & 4) != 0;
    const bool b2 = (jl & 2) != 0;
    const bool b1 = (jl & 1) != 0;

    // xor8 (DPP row_ror:8 == xor8 within the 16-row): 24 -> 12
    float w[12];
    #pragma unroll
    for (int j = 0; j < 12; ++j) {
        const float lo = accA[j], hi = accA[j + 12];
        w[j] = (b8 ? hi : lo) + dppf<0x128>(b8 ? lo : hi);
    }
    // xor2 (quad_perm [2,3,0,1]): 12 -> 6
    float u[6];
    #pragma unroll
    for (int j = 0; j < 6; ++j) {
        const float lo = w[j], hi = w[j + 6];
        u[j] = (b2 ? hi : lo) + dppf<0x4E>(b2 ? lo : hi);
    }
    // xor1 (quad_perm [1,0,3,2]): 6 -> 3
    float r0, r1, r2;
    {
        const float l0 = u[0], h0 = u[3];
        r0 = (b1 ? h0 : l0) + dppf<0xB1>(b1 ? l0 : h0);
        const float l1 = u[1], h1 = u[4];
        r1 = (b1 ? h1 : l1) + dppf<0xB1>(b1 ? l1 : h1);
        const float l2 = u[2], h2 = u[5];
        r2 = (b1 ? h2 : l2) + dppf<0xB1>(b1 ? l2 : h2);
    }
    // xor4: full butterfly on the remaining 3 (partner jl^4 holds same dims)
    r0 += __shfl_xor(r0, 4, 64);
    r1 += __shfl_xor(r1, 4, 64);
    r2 += __shfl_xor(r2, 4, 64);

    // lane's 3 dims: 24q + 12*b8 + 6*b2 + 3*b1 + {0,1,2}; xor4-pair splits
    // the store (even b4: dims +0,+1; odd b4: dim +2). Covers dims 0..95.
    const int base = 24 * q + (b8 ? 12 : 0) + (b2 ? 6 : 0) + (b1 ? 3 : 0);
    if (!b4) {
        orow[base]     = r0 * inv;
        orow[base + 1] = r1 * inv;
    } else {
        orow[base + 2] = r2 * inv;
    }
}

extern "C" void kernel_launch(void* const* d_in, const int* in_sizes, int n_in,
                              void* d_out, int out_size, void* d_ws, size_t ws_size,
                              hipStream_t stream) {
    const float* hidden = (const float*)d_in[0];
    const float* W      = (const float*)d_in[1];
    const int*   seg    = (const int*)d_in[2];
    const int*   nbr    = (const int*)d_in[3];
    float*       out    = (float*)d_out;

    const int Ddim = in_sizes[1];           // 100
    const int n    = in_sizes[0] / Ddim;    // 50000
    const int P    = in_sizes[2];           // ~1.3M pairs

    // ws layout: row_ptr (n+1 ints) | hb (n*ROWU uints, 256B-aligned)
    int* row_ptr = (int*)d_ws;
    size_t hb_off = (((size_t)(n + 1) * 4) + 255) & ~(size_t)255;
    unsigned int* hb = (unsigned int*)((char*)d_ws + hb_off);

    const int total25 = n * 25;             // float4-groups in hidden
    const int tmax    = (P > total25) ? P : total25;
    hipLaunchKernelGGL(prep_kernel, dim3((tmax + 255) / 256), dim3(256), 0, stream,
                       seg, row_ptr, hidden, hb, n, P, total25);
    hipLaunchKernelGGL(gat_agg_kernel, dim3((n + NPB - 1) / NPB), dim3(64 * NPB),
                       0, stream, hidden, W, nbr, row_ptr, hb, out, n, P);
}

// Round 9
// 157.026 us; speedup vs baseline: 1.6043x; 1.4040x over previous
//
#include <hip/hip_runtime.h>
#include <math.h>

#define D 100
#define NEG_SLOPE 0.2f
#define CHUNK 16
#define ROWU 52          // uints per packed-f16 row, padded 50->52 for 16B align
#define NPB 2            // nodes (waves) per block

// compiler-only memory barrier (validated R17: same-wave LDS is pipe-ordered)
#define COMPILER_FENCE() asm volatile("" ::: "memory")

typedef _Float16 f16x2 __attribute__((ext_vector_type(2)));
union U32H2 { unsigned int u; f16x2 h; };

__device__ __forceinline__ unsigned int pkh2(float x, float y) {
    U32H2 c; c.h.x = (_Float16)x; c.h.y = (_Float16)y; return c.u;
}

// 2-wide f16 dot + fp32 accumulate: v_dot2_f32_f16
__device__ __forceinline__ float dot2u(unsigned int au, unsigned int xu, float acc) {
#if __has_builtin(__builtin_amdgcn_fdot2)
    U32H2 a, x; a.u = au; x.u = xu;
    return __builtin_amdgcn_fdot2(a.h, x.h, acc, false);
#else
    U32H2 a, x; a.u = au; x.u = xu;
    return acc + (float)a.h.x * (float)x.h.x + (float)a.h.y * (float)x.h.y;
#endif
}

// DPP cross-lane (VALU pipe).
template<int CTRL>
__device__ __forceinline__ float dppf(float x) {
    return __uint_as_float((unsigned)__builtin_amdgcn_update_dpp(
        0, (int)__float_as_uint(x), CTRL, 0xF, 0xF, true));
}
__device__ __forceinline__ float red16_max(float x) {
    x = fmaxf(x, dppf<0xB1>(x));    // quad_perm xor1
    x = fmaxf(x, dppf<0x4E>(x));    // quad_perm xor2
    x = fmaxf(x, dppf<0x124>(x));   // row_ror:4
    x = fmaxf(x, dppf<0x128>(x));   // row_ror:8
    return x;
}
__device__ __forceinline__ float red16_sum(float x) {
    x += dppf<0xB1>(x);
    x += dppf<0x4E>(x);
    x += dppf<0x124>(x);
    x += dppf<0x128>(x);
    return x;
}

// Fused prep: t < P: row_ptr boundary scatter; t < total25: fp32 -> f16 pack.
__global__ void prep_kernel(const int* __restrict__ seg,
                            int* __restrict__ row_ptr,
                            const float* __restrict__ hidden,
                            unsigned int* __restrict__ hb,
                            int n, int P, int total25)
{
    int t = blockIdx.x * blockDim.x + threadIdx.x;
    if (t < P) {
        int s0 = seg[t];
        if (t == 0)
            for (int v = 0; v <= s0; v++) row_ptr[v] = 0;
        int s1 = (t + 1 < P) ? seg[t + 1] : n;
        for (int v = s0 + 1; v <= s1; v++) row_ptr[v] = t + 1;
    }
    if (t < total25) {
        int node = t / 25, k = t - node * 25;   // 25 float4-groups per row
        float4 f = ((const float4*)hidden)[t];
        *(uint2*)&hb[node * ROWU + 2 * k] =
            make_uint2(pkh2(f.x, f.y), pkh2(f.z, f.w));
    }
}

// accumulate one uint4 (8 f16 dims) into accA[b..b+7] via v_fma_mix
#define ACCU4(b, X) do {                                                      \
    U32H2 t_;                                                                 \
    t_.u = (X).x; accA[(b)+0] = fmaf((float)t_.h.x, e, accA[(b)+0]);          \
                  accA[(b)+1] = fmaf((float)t_.h.y, e, accA[(b)+1]);          \
    t_.u = (X).y; accA[(b)+2] = fmaf((float)t_.h.x, e, accA[(b)+2]);          \
                  accA[(b)+3] = fmaf((float)t_.h.y, e, accA[(b)+3]);          \
    t_.u = (X).z; accA[(b)+4] = fmaf((float)t_.h.x, e, accA[(b)+4]);          \
                  accA[(b)+5] = fmaf((float)t_.h.y, e, accA[(b)+5]);          \
    t_.u = (X).w; accA[(b)+6] = fmaf((float)t_.h.x, e, accA[(b)+6]);          \
                  accA[(b)+7] = fmaf((float)t_.h.y, e, accA[(b)+7]);          \
} while (0)

// One wave per node, CHUNK=16, 4 lanes/pair. R9 = R7's register-accumulator
// main loop + zero-LDS split-butterfly epilogue, with the SPILL fixed:
// R6/R8 showed peak pressure (~68: accA24+accT4+hoisted-a14+x14+temps12)
// just over the (128,8) 64-VGPR budget -> allocator dumped accA to scratch
// (VGPR 32, WRITE 322MB, 141us). Fixes: (1) a-fragments re-read from LDS
// per chunk through ONE reused uint4 (broadcast reads; frees ~10 persistent
// regs), (2) in-place butterfly so epilogue peak <= loop peak, (3)
// __launch_bounds__(128,7): budget 73 — if the kernel fits <=64 it still
// runs 8 waves/SIMD at runtime; if it needs 65-73 we lose one wave instead
// of spilling everything. LDS = s_hwp only (0.42KB) -> LDS never caps waves.
__launch_bounds__(64 * NPB, 7)
__global__ void gat_agg_kernel(const float* __restrict__ hidden,
                               const float* __restrict__ W,
                               const int* __restrict__ nbr,
                               const int* __restrict__ row_ptr,
                               const unsigned int* __restrict__ hb,
                               float* __restrict__ out,
                               int n, int P)
{
    __shared__ __align__(16) unsigned int s_hwp[NPB][ROWU];       // 0.42 KB

    const int lane = threadIdx.x & 63;
    const int wid  = threadIdx.x >> 6;
    const int v    = blockIdx.x * NPB + wid;
    if (v >= n) return;          // wave-uniform exit; no block barriers used

    // hw[d] = hidden[v][d] * W[d] (fp32 product, f16-packed into LDS)
    if (lane < 50) {
        float2 h2 = ((const float2*)(hidden + (long)v * D))[lane];
        float2 w2 = ((const float2*)W)[lane];
        s_hwp[wid][lane] = pkh2(h2.x * w2.x, h2.y * w2.y);
    }
    COMPILER_FENCE();

    const int start = row_ptr[v];
    const int end   = row_ptr[v + 1];

    if (end <= start) {          // empty segment: zeros (matches reference)
        if (lane < D / 2)
            ((float2*)(out + (long)v * D))[lane] = make_float2(0.f, 0.f);
        return;
    }

    const int q  = lane >> 4;    // quarter 0..3: uint4s q*3..q*3+2 (+tail on q0)
    const int jl = lane & 15;    // pair slot within the 16-chunk
    const int t0 = q * 3;

    // a-fragment base (LDS); re-read per chunk via one reused register —
    // broadcast within each 16-lane group, 4 distinct banks across the wave
    const uint4* aq = ((const uint4*)&s_hwp[wid][0]) + t0;

    // register accumulators: quarter dims 24q..24q+23, plus tail 96..99 on q0
    float accA[24];
    float accT[4];
    #pragma unroll
    for (int i = 0; i < 24; ++i) accA[i] = 0.f;
    #pragma unroll
    for (int i = 0; i < 4; ++i) accT[i] = 0.f;

    float m = -INFINITY, z = 0.f;

    for (int c = start; c < end; c += CHUNK) {
        const int  cnt = min(CHUNK, end - c);
        const bool pv  = jl < cnt;

        // neighbor index: coalesced masked load. invalid lanes use row 0
        // (finite, in-bounds, L1-hot); e=0 masks them later.
        const int nbv = pv ? nbr[c + jl] : 0;
        const uint4* row16 = ((const uint4*)hb) + nbv * (ROWU / 4) + t0;

        // ---- f16 quarter-row gather (3x16B + 8B tail on q0), fdot2 ----
        uint4 x0 = row16[0], x1 = row16[1], x2 = row16[2];
        uint2 xt = make_uint2(0u, 0u);
        if (q == 0) xt = *(const uint2*)&hb[nbv * ROWU + 48];   // dims 96..99

        float p0 = 0.f, p1 = 0.f, p2 = 0.f, p3 = 0.f;
        uint4 a;
        a = aq[0]; p0 = dot2u(a.x, x0.x, p0); p1 = dot2u(a.y, x0.y, p1);
                   p2 = dot2u(a.z, x0.z, p2); p3 = dot2u(a.w, x0.w, p3);
        a = aq[1]; p0 = dot2u(a.x, x1.x, p0); p1 = dot2u(a.y, x1.y, p1);
                   p2 = dot2u(a.z, x1.z, p2); p3 = dot2u(a.w, x1.w, p3);
        a = aq[2]; p0 = dot2u(a.x, x2.x, p0); p1 = dot2u(a.y, x2.y, p1);
                   p2 = dot2u(a.z, x2.z, p2); p3 = dot2u(a.w, x2.w, p3);
        if (q == 0) {
            const uint2 at = *(const uint2*)&s_hwp[wid][48];
            p0 = dot2u(at.x, xt.x, p0);
            p1 = dot2u(at.y, xt.y, p1);
        }

        float part = (p0 + p1) + (p2 + p3);
        part += __shfl_xor(part, 16, 64);    // combine quarters; after these
        part += __shfl_xor(part, 32, 64);    // ALL 4 lanes hold the pair score
        const float s = pv ? (part >= 0.f ? part : NEG_SLOPE * part)
                           : -INFINITY;

        // ---- online softmax over the 16 pairs (DPP trees, wave-uniform m) --
        const float m_new = fmaxf(m, red16_max(s));
        const float e     = pv ? __expf(s - m_new) : 0.f;
        const float gsum  = red16_sum(e);

        if (m_new != m) {                    // wave-uniform; scale==1 if equal
            const float scale = __expf(m - m_new);   // first chunk: 0
            z *= scale;
            #pragma unroll
            for (int i = 0; i < 24; ++i) accA[i] *= scale;
            #pragma unroll
            for (int i = 0; i < 4; ++i) accT[i] *= scale;
            m = m_new;
        }
        z += gsum;

        // ---- accumulate e * row into register accumulators (v_fma_mix) ----
        ACCU4(0,  x0);
        ACCU4(8,  x1);
        ACCU4(16, x2);
        if (q == 0) {
            U32H2 t_;
            t_.u = xt.x; accT[0] = fmaf((float)t_.h.x, e, accT[0]);
                         accT[1] = fmaf((float)t_.h.y, e, accT[1]);
            t_.u = xt.y; accT[2] = fmaf((float)t_.h.x, e, accT[2]);
                         accT[3] = fmaf((float)t_.h.y, e, accT[3]);
        }
    }

    const float inv = 1.f / z;               // z wave-uniform
    float* orow = out + (long)v * D;

    // ---- tail first (frees accT early): full DPP-16 reduce of dims 96..99 --
    const float T0 = red16_sum(accT[0]) * inv;
    const float T1 = red16_sum(accT[1]) * inv;
    const float T2 = red16_sum(accT[2]) * inv;
    const float T3 = red16_sum(accT[3]) * inv;
    if (lane == 0) ((float2*)orow)[48] = make_float2(T0, T1);
    if (lane == 1) ((float2*)orow)[49] = make_float2(T2, T3);

    // ---- split-butterfly cross-pair reduction (registers only, IN PLACE) --
    // each exchange halves the payload; kept half selected by a jl bit.
    // DPP input = the half this lane is NOT keeping (what the partner needs).
    const bool b8 = (jl & 8) != 0;
    const bool b4 = (jl & 4) != 0;
    const bool b2 = (jl & 2) != 0;
    const bool b1 = (jl & 1) != 0;

    // xor8 (row_ror:8 == xor8 within the 16-row): 24 -> 12
    #pragma unroll
    for (int j = 0; j < 12; ++j) {
        const float lo = accA[j], hi = accA[j + 12];
        accA[j] = (b8 ? hi : lo) + dppf<0x128>(b8 ? lo : hi);
    }
    // xor2 (quad_perm [2,3,0,1]): 12 -> 6
    #pragma unroll
    for (int j = 0; j < 6; ++j) {
        const float lo = accA[j], hi = accA[j + 6];
        accA[j] = (b2 ? hi : lo) + dppf<0x4E>(b2 ? lo : hi);
    }
    // xor1 (quad_perm [1,0,3,2]): 6 -> 3
    #pragma unroll
    for (int j = 0; j < 3; ++j) {
        const float lo = accA[j], hi = accA[j + 3];
        accA[j] = (b1 ? hi : lo) + dppf<0xB1>(b1 ? lo : hi);
    }
    // xor4: full butterfly on the remaining 3 (partner jl^4 holds same dims)
    accA[0] += __shfl_xor(accA[0], 4, 64);
    accA[1] += __shfl_xor(accA[1], 4, 64);
    accA[2] += __shfl_xor(accA[2], 4, 64);

    // lane's 3 dims: 24q + 12*b8 + 6*b2 + 3*b1 + {0,1,2}; xor4-pair splits
    // the store (even b4: dims +0,+1; odd b4: dim +2). Covers dims 0..95.
    const int base = 24 * q + (b8 ? 12 : 0) + (b2 ? 6 : 0) + (b1 ? 3 : 0);
    if (!b4) {
        orow[base]     = accA[0] * inv;
        orow[base + 1] = accA[1] * inv;
    } else {
        orow[base + 2] = accA[2] * inv;
    }
}

extern "C" void kernel_launch(void* const* d_in, const int* in_sizes, int n_in,
                              void* d_out, int out_size, void* d_ws, size_t ws_size,
                              hipStream_t stream) {
    const float* hidden = (const float*)d_in[0];
    const float* W      = (const float*)d_in[1];
    const int*   seg    = (const int*)d_in[2];
    const int*   nbr    = (const int*)d_in[3];
    float*       out    = (float*)d_out;

    const int Ddim = in_sizes[1];           // 100
    const int n    = in_sizes[0] / Ddim;    // 50000
    const int P    = in_sizes[2];           // ~1.3M pairs

    // ws layout: row_ptr (n+1 ints) | hb (n*ROWU uints, 256B-aligned)
    int* row_ptr = (int*)d_ws;
    size_t hb_off = (((size_t)(n + 1) * 4) + 255) & ~(size_t)255;
    unsigned int* hb = (unsigned int*)((char*)d_ws + hb_off);

    const int total25 = n * 25;             // float4-groups in hidden
    const int tmax    = (P > total25) ? P : total25;
    hipLaunchKernelGGL(prep_kernel, dim3((tmax + 255) / 256), dim3(256), 0, stream,
                       seg, row_ptr, hidden, hb, n, P, total25);
    hipLaunchKernelGGL(gat_agg_kernel, dim3((n + NPB - 1) / NPB), dim3(64 * NPB),
                       0, stream, hidden, W, nbr, row_ptr, hb, out, n, P);
}